// Round 4
// baseline (188.944 us; speedup 1.0000x reference)
//
#include <hip/hip_runtime.h>
#include <stdint.h>

typedef __bf16 bf16;
typedef __bf16 bf16x4 __attribute__((ext_vector_type(4)));
typedef __bf16 bf16x8 __attribute__((ext_vector_type(8)));
typedef float f32x4 __attribute__((ext_vector_type(4)));

#define MFMA16(a, b, c) __builtin_amdgcn_mfma_f32_16x16x32_bf16((a), (b), (c), 0, 0, 0)

#define EMBED 1024
#define SEQ   2048
#define MROWS 4096
// 0.125 * log2(e): Q is pre-scaled so attn can use native v_exp_f32 (exp2).
#define ATTN_QSCALE 0.1803368801111f

__device__ __forceinline__ void gl2lds16(const bf16* g, bf16* l) {
    __builtin_amdgcn_global_load_lds(
        (const __attribute__((address_space(1))) void*)g,
        (__attribute__((address_space(3))) void*)l,
        16, 0, 0);
}

// ---------------------------------------------------------------------------
// fused fp32 -> bf16 cast of x + 4 weight matrices (contiguous dst region)
// ---------------------------------------------------------------------------
__global__ __launch_bounds__(256) void cast_all_kernel(
    const float* __restrict__ x,  const float* __restrict__ Wq,
    const float* __restrict__ Wk, const float* __restrict__ Wv,
    const float* __restrict__ Wo, bf16* __restrict__ dst) {
    const int blk = blockIdx.x;
    const float* src;
    size_t so, dofs;
    if (blk < 2048) {
        src = x; so = (size_t)blk * 2048; dofs = so;
    } else {
        const int w = (blk - 2048) >> 9;
        so  = (size_t)((blk - 2048) & 511) * 2048;
        src = (w == 0) ? Wq : (w == 1) ? Wk : (w == 2) ? Wv : Wo;
        dofs = (size_t)(4 + w) * 1024 * 1024 + so;
    }
    const size_t i = (size_t)threadIdx.x * 8;
    float4 a = *(const float4*)(src + so + i);
    float4 b = *(const float4*)(src + so + i + 4);
    bf16x8 o;
    o[0] = (bf16)a.x; o[1] = (bf16)a.y; o[2] = (bf16)a.z; o[3] = (bf16)a.w;
    o[4] = (bf16)b.x; o[5] = (bf16)b.y; o[6] = (bf16)b.z; o[7] = (bf16)b.w;
    *(bf16x8*)(dst + dofs + i) = o;
}

// ---------------------------------------------------------------------------
// Q/K GEMM path: 128x128 tile, BK=64, 4 waves 2x2, XOR-swizzled LDS.
// Double-buffered 1-deep pipeline: vmcnt(0) -> s_barrier -> stage(k+1) ->
// compute(k).
// ---------------------------------------------------------------------------
template <bool SCALE>
__device__ __forceinline__ void gemm_tile(const bf16* __restrict__ A,
                                          const bf16* __restrict__ W,
                                          const float* __restrict__ bias,
                                          bf16* __restrict__ C,
                                          int m0, int n0, bf16* smem) {
    const int lane = threadIdx.x & 63;
    const int wv   = threadIdx.x >> 6;
    const int wm   = (wv >> 1) * 64;
    const int wn   = (wv & 1) * 64;
    const int fr   = lane & 15;
    const int quad = lane >> 4;
    const int srow = wv * 8 + (lane >> 3);
    const int swz  = (((lane & 7) ^ ((lane >> 3) & 7))) * 8;

    f32x4 acc[4][4];
#pragma unroll
    for (int mt = 0; mt < 4; ++mt)
#pragma unroll
        for (int nt = 0; nt < 4; ++nt)
            acc[mt][nt] = (f32x4){0.f, 0.f, 0.f, 0.f};

    auto stage = [&](int kt, int bb) {
        bf16* As = smem + bb * 16384;
        bf16* Bs = As + 8192;
        const int k0 = kt * 64;
#pragma unroll
        for (int i = 0; i < 4; ++i) {
            gl2lds16(A + (size_t)(m0 + i * 32 + srow) * 1024 + k0 + swz,
                     &As[(i * 32 + wv * 8) * 64]);
            gl2lds16(W + (size_t)(n0 + i * 32 + srow) * 1024 + k0 + swz,
                     &Bs[(i * 32 + wv * 8) * 64]);
        }
    };

    stage(0, 0);
#pragma unroll
    for (int kt = 0; kt < 16; ++kt) {
        const int bb = kt & 1;
        asm volatile("s_waitcnt vmcnt(0)" ::: "memory");
        __builtin_amdgcn_s_barrier();
        if (kt < 15) stage(kt + 1, bb ^ 1);
        const bf16* As = smem + bb * 16384;
        const bf16* Bs = As + 8192;
#pragma unroll
        for (int ks = 0; ks < 2; ++ks) {
            const int fcol = ((ks * 4 + quad) ^ (fr & 7)) * 8;
            bf16x8 af[4], bfr[4];
#pragma unroll
            for (int t = 0; t < 4; ++t) {
                af[t]  = *(const bf16x8*)&As[(wm + t * 16 + fr) * 64 + fcol];
                bfr[t] = *(const bf16x8*)&Bs[(wn + t * 16 + fr) * 64 + fcol];
            }
            __builtin_amdgcn_s_setprio(1);
#pragma unroll
            for (int mt = 0; mt < 4; ++mt)
#pragma unroll
                for (int nt = 0; nt < 4; ++nt)
                    acc[mt][nt] = MFMA16(af[mt], bfr[nt], acc[mt][nt]);
            __builtin_amdgcn_s_setprio(0);
        }
    }

    float bv[4];
#pragma unroll
    for (int nt = 0; nt < 4; ++nt)
        bv[nt] = bias[n0 + wn + nt * 16 + fr];
    const int row4 = quad * 4;
#pragma unroll
    for (int mt = 0; mt < 4; ++mt)
#pragma unroll
        for (int nt = 0; nt < 4; ++nt)
#pragma unroll
            for (int r = 0; r < 4; ++r) {
                int m = m0 + wm + mt * 16 + row4 + r;
                int n = n0 + wn + nt * 16 + fr;
                float v = acc[mt][nt][r] + bv[nt];
                if (SCALE) v *= ATTN_QSCALE;
                C[(size_t)m * 1024 + n] = (bf16)v;
            }
}

// ---------------------------------------------------------------------------
// V^T GEMM path: swapped-operand MFMA + LDS round-trip transpose epilogue.
// Token axis of VT is PERMUTED within each 32-token chunk:
//   c' = quad*8 + t'*4 + r   <-  o = t'*16 + quad*4 + r
// ---------------------------------------------------------------------------
__device__ __forceinline__ void v_tile(const bf16* __restrict__ x,
                                       const bf16* __restrict__ Wv,
                                       const float* __restrict__ bias,
                                       bf16* __restrict__ VT,
                                       int m0, int n0, bf16* smem) {
    const int lane = threadIdx.x & 63;
    const int wv   = threadIdx.x >> 6;
    const int wmW  = (wv >> 1) * 64;
    const int wnT  = (wv & 1) * 64;
    const int f    = lane & 15;
    const int quad = lane >> 4;
    const int srow = wv * 8 + (lane >> 3);
    const int swz  = (((lane & 7) ^ ((lane >> 3) & 7))) * 8;

    f32x4 acc[4][4];
#pragma unroll
    for (int mt = 0; mt < 4; ++mt)
#pragma unroll
        for (int nt = 0; nt < 4; ++nt)
            acc[mt][nt] = (f32x4){0.f, 0.f, 0.f, 0.f};

    auto stage = [&](int kt, int bb) {
        bf16* As = smem + bb * 16384;
        bf16* Bs = As + 8192;
        const int k0 = kt * 64;
#pragma unroll
        for (int i = 0; i < 4; ++i) {
            gl2lds16(x  + (size_t)(m0 + i * 32 + srow) * 1024 + k0 + swz,
                     &As[(i * 32 + wv * 8) * 64]);
            gl2lds16(Wv + (size_t)(n0 + i * 32 + srow) * 1024 + k0 + swz,
                     &Bs[(i * 32 + wv * 8) * 64]);
        }
    };

    stage(0, 0);
#pragma unroll
    for (int kt = 0; kt < 16; ++kt) {
        const int bb = kt & 1;
        asm volatile("s_waitcnt vmcnt(0)" ::: "memory");
        __builtin_amdgcn_s_barrier();
        if (kt < 15) stage(kt + 1, bb ^ 1);
        const bf16* As = smem + bb * 16384;
        const bf16* Bs = As + 8192;
#pragma unroll
        for (int ks = 0; ks < 2; ++ks) {
            const int fcol = ((ks * 4 + quad) ^ (f & 7)) * 8;
            bf16x8 wf[4], xf[4];
#pragma unroll
            for (int t = 0; t < 4; ++t) {
                wf[t] = *(const bf16x8*)&Bs[(wmW + t * 16 + f) * 64 + fcol];
                xf[t] = *(const bf16x8*)&As[(wnT + t * 16 + f) * 64 + fcol];
            }
            __builtin_amdgcn_s_setprio(1);
#pragma unroll
            for (int mt = 0; mt < 4; ++mt)
#pragma unroll
                for (int nt = 0; nt < 4; ++nt)
                    acc[mt][nt] = MFMA16(wf[mt], xf[nt], acc[mt][nt]);
            __builtin_amdgcn_s_setprio(0);
        }
    }

    float4 b4[4];
#pragma unroll
    for (int mt = 0; mt < 4; ++mt)
        b4[mt] = *(const float4*)&bias[n0 + wmW + mt * 16 + quad * 4];

    __syncthreads();   // all waves done computing before smem reuse as scratch

#pragma unroll
    for (int mt = 0; mt < 4; ++mt)
#pragma unroll
        for (int nt = 0; nt < 4; ++nt) {
            const int tok = wnT + nt * 16 + f;
#pragma unroll
            for (int r = 0; r < 4; ++r) {
                const float bvr = (r == 0) ? b4[mt].x : (r == 1) ? b4[mt].y
                                : (r == 2) ? b4[mt].z : b4[mt].w;
                smem[(wmW + mt * 16 + quad * 4 + r) * 136 + tok] =
                    (bf16)(acc[mt][nt][r] + bvr);
            }
        }
    __syncthreads();

    const int n_r  = threadIdx.x >> 4;
    const int t8   = (threadIdx.x & 15) * 8;       // permuted positions [t8, t8+8)
    const int base = t8 & ~31;                     // 32-token chunk base
    const int u4   = ((t8 >> 3) & 3) * 4;          // quad-group within chunk
    const int bb   = m0 >> 11;
    const int tokg = (m0 & 2047) + t8;
#pragma unroll
    for (int p = 0; p < 8; ++p) {
        const int n_loc = p * 16 + n_r;
        const bf16* row = &smem[n_loc * 136];
        bf16x4 a = *(const bf16x4*)&row[base + u4];         // orig tokens t'=0
        bf16x4 b = *(const bf16x4*)&row[base + 16 + u4];    // orig tokens t'=1
        bf16x8 v = {a[0], a[1], a[2], a[3], b[0], b[1], b[2], b[3]};
        *(bf16x8*)&VT[((size_t)(bb * 1024 + n0 + n_loc)) * 2048 + tokg] = v;
    }
}

// merged Q/K/V projection, XCD-chunked block swizzle (768 = 8 XCD x 96).
// m0 varies fastest within a chunk -> one 128-row weight panel stays hot
// in the XCD's private L2.
__global__ __launch_bounds__(256) void qkv_kernel(
    const bf16* __restrict__ x,
    const bf16* __restrict__ Wq, const float* __restrict__ bq,
    const bf16* __restrict__ Wk, const float* __restrict__ bk,
    const bf16* __restrict__ Wv, const float* __restrict__ bv,
    bf16* __restrict__ Q, bf16* __restrict__ K, bf16* __restrict__ VT) {
    __shared__ __align__(16) bf16 smem[32768];   // 2 bufs x (As 16KB + Bs 16KB)
    const int lin   = blockIdx.y * 32 + blockIdx.x;   // 0..767
    const int sw    = (lin & 7) * 96 + (lin >> 3);    // XCD chunks of 96
    const int which = sw >> 8;
    const int rem   = sw & 255;
    const int n0    = (rem >> 5) * 128;
    const int m0    = (rem & 31) * 128;
    if (which == 0)      gemm_tile<true>(x, Wq, bq, Q, m0, n0, smem);
    else if (which == 1) gemm_tile<false>(x, Wk, bk, K, m0, n0, smem);
    else                 v_tile(x, Wv, bv, VT, m0, n0, smem);
}

// ---------------------------------------------------------------------------
// O-proj GEMM fused with softmax-combine.  128x64 tile, BK=64 == head dim,
// so each K-step covers exactly one head h = kt.  A-tile is reg-staged:
// a = (Opart0 + Opart1) * 1/(l0+l1), normalized in VALU, ds_write'd into the
// same XOR-swizzled LDS layout global_load_lds would have produced.
// Eliminates the separate combine kernel and the O round-trip.
// ---------------------------------------------------------------------------
__global__ __launch_bounds__(256) void oproj_kernel(
    const bf16* __restrict__ Opart, const float* __restrict__ lpart,
    const bf16* __restrict__ W, const float* __restrict__ bias,
    float* __restrict__ C) {
    const int lin = blockIdx.y * 32 + blockIdx.x;   // 0..511
    const int sw  = (lin & 7) * 64 + (lin >> 3);    // XCD chunks of 64
    const int m0  = (sw & 31) * 128;
    const int n0  = (sw >> 5) * 64;

    __shared__ __align__(16) bf16 smem[2 * 12288];  // 2 bufs x (As 16KB + Bs 8KB)

    const int lane = threadIdx.x & 63;
    const int wv   = threadIdx.x >> 6;
    const int wm   = (wv >> 1) * 64;
    const int wn   = (wv & 1) * 32;
    const int fr   = lane & 15;
    const int quad = lane >> 4;
    const int srow = wv * 8 + (lane >> 3);
    const int swz  = (((lane & 7) ^ ((lane >> 3) & 7))) * 8;

    f32x4 acc[4][2];
#pragma unroll
    for (int mt = 0; mt < 4; ++mt)
#pragma unroll
        for (int nt = 0; nt < 2; ++nt)
            acc[mt][nt] = (f32x4){0.f, 0.f, 0.f, 0.f};

    bf16x8 a0[4], a1[4];
    float  l0[4], l1[4];

    // issue A loads (16 vmem ops) -- h = kt since BK == 64 == head dim
    auto loadA = [&](int kt) {
#pragma unroll
        for (int i = 0; i < 4; ++i) {
            const int row = m0 + i * 32 + srow;
            const int b_  = row >> 11;
            const int tok = row & 2047;
            const size_t off = (size_t)row * 1024 + kt * 64 + swz;
            a0[i] = *(const bf16x8*)&Opart[off];
            a1[i] = *(const bf16x8*)&Opart[(size_t)MROWS * 1024 + off];
            l0[i] = lpart[((size_t)b_ * 16 + kt) * SEQ + tok];
            l1[i] = lpart[((size_t)(2 + b_) * 16 + kt) * SEQ + tok];
        }
    };
    // normalize + ds_write into gl2lds-equivalent swizzled layout
    auto writeA = [&](int bb) {
        bf16* As = smem + bb * 12288;
#pragma unroll
        for (int i = 0; i < 4; ++i) {
            const float inv = 1.0f / (l0[i] + l1[i]);
            bf16x8 o;
#pragma unroll
            for (int j = 0; j < 8; ++j)
                o[j] = (bf16)(((float)a0[i][j] + (float)a1[i][j]) * inv);
            *(bf16x8*)&As[(i * 32 + srow) * 64 + (lane & 7) * 8] = o;
        }
    };
    auto stageW = [&](int kt, int bb) {
        bf16* Bs = smem + bb * 12288 + 8192;
#pragma unroll
        for (int i = 0; i < 2; ++i)
            gl2lds16(W + (size_t)(n0 + i * 32 + srow) * 1024 + kt * 64 + swz,
                     &Bs[(i * 32 + wv * 8) * 64]);
    };

    loadA(0);
    stageW(0, 0);
    writeA(0);                                   // compiler waits the A regs
    asm volatile("s_waitcnt vmcnt(0) lgkmcnt(0)" ::: "memory");
    __builtin_amdgcn_s_barrier();

#pragma unroll
    for (int kt = 0; kt < 16; ++kt) {
        const int bb = kt & 1;
        if (kt < 15) { loadA(kt + 1); stageW(kt + 1, bb ^ 1); }
        const bf16* As = smem + bb * 12288;
        const bf16* Bs = As + 8192;
#pragma unroll
        for (int ks = 0; ks < 2; ++ks) {
            const int fcol = ((ks * 4 + quad) ^ (fr & 7)) * 8;
            bf16x8 af[4], bfr[2];
#pragma unroll
            for (int t = 0; t < 4; ++t)
                af[t] = *(const bf16x8*)&As[(wm + t * 16 + fr) * 64 + fcol];
#pragma unroll
            for (int t = 0; t < 2; ++t)
                bfr[t] = *(const bf16x8*)&Bs[(wn + t * 16 + fr) * 64 + fcol];
            __builtin_amdgcn_s_setprio(1);
#pragma unroll
            for (int mt = 0; mt < 4; ++mt)
#pragma unroll
                for (int nt = 0; nt < 2; ++nt)
                    acc[mt][nt] = MFMA16(af[mt], bfr[nt], acc[mt][nt]);
            __builtin_amdgcn_s_setprio(0);
        }
        if (kt < 15) {
            writeA(bb ^ 1);                      // A regs auto-waited
            asm volatile("s_waitcnt vmcnt(0) lgkmcnt(0)" ::: "memory");
            __builtin_amdgcn_s_barrier();
        }
    }

    float bv[2];
#pragma unroll
    for (int nt = 0; nt < 2; ++nt)
        bv[nt] = bias[n0 + wn + nt * 16 + fr];
    const int row4 = quad * 4;
#pragma unroll
    for (int mt = 0; mt < 4; ++mt)
#pragma unroll
        for (int nt = 0; nt < 2; ++nt)
#pragma unroll
            for (int r = 0; r < 4; ++r) {
                int m = m0 + wm + mt * 16 + row4 + r;
                int n = n0 + wn + nt * 16 + fr;
                C[(size_t)m * 1024 + n] = acc[mt][nt][r] + bv[nt];
            }
}

// ---------------------------------------------------------------------------
// Flash attention v12: same verified ring-4 / counted-vmcnt(8) schedule as
// v11 (4 gl2lds per tile -> vmcnt(8) keeps exactly 2 tiles in flight), plus
// XCD-chunked block swizzle: 64 consecutive blocks per XCD -> only 4 (b,h)
// K/V panels per private L2 instead of all 32.
// ---------------------------------------------------------------------------
__global__ __launch_bounds__(256, 2) void attn_kernel(
    const bf16* __restrict__ Q, const bf16* __restrict__ K,
    const bf16* __restrict__ VT, bf16* __restrict__ Opart,
    float* __restrict__ lpart) {
    const int tid  = threadIdx.x;
    const int lane = tid & 63;
    const int wv   = tid >> 6;       // 0..3
    const int quad = lane >> 4;
    const int f    = lane & 15;
    const int lin  = blockIdx.y * 16 + blockIdx.x;   // 0..511
    const int sw   = (lin & 7) * 64 + (lin >> 3);    // XCD chunks of 64
    const int qh   = sw & 15;
    const int bh   = sw >> 4;        // 0..31
    const int qt   = qh >> 1;
    const int half = qh & 1;
    const int q0   = qt * 256;
    const int kvb  = half * 1024;
    const int b    = bh >> 4;
    const int h    = bh & 15;

    const bf16* Qp = Q + ((size_t)b * SEQ) * 1024 + (size_t)h * 64;
    const bf16* Kp = K + ((size_t)b * SEQ) * 1024 + (size_t)h * 64;
    const bf16* Vp = VT + ((size_t)(b * 1024 + h * 64)) * 2048;   // [d][tok']
    bf16*  Op = Opart + (size_t)half * MROWS * 1024
                      + ((size_t)b * SEQ) * 1024 + (size_t)h * 64;
    float* lp = lpart + ((size_t)(half * 2 + b) * 16 + h) * SEQ;

    __shared__ bf16 Ks[4][64 * 64];    // ring-4 [kv][d], swizzled 16B groups
    __shared__ bf16 VTs[4][64 * 64];   // ring-4 [d][kv'], swizzled 16B groups

    // Q fragments: wave handles 64 q-rows (4 groups of 16); pre-scaled.
    bf16x8 qf[4][2];
#pragma unroll
    for (int qg = 0; qg < 4; ++qg) {
        const bf16* qrow = Qp + (size_t)(q0 + wv * 64 + qg * 16 + f) * 1024;
        qf[qg][0] = *(const bf16x8*)(qrow + quad * 8);
        qf[qg][1] = *(const bf16x8*)(qrow + 32 + quad * 8);
    }

    const int srow = wv * 8 + (lane >> 3);
    const int swz  = (((lane & 7) ^ ((lane >> 3) & 7))) * 8;
    auto stageK = [&](int t, int bb) {
        const int kv0 = kvb + t * 64;
#pragma unroll
        for (int i = 0; i < 2; ++i)
            gl2lds16(Kp + (size_t)(kv0 + i * 32 + srow) * 1024 + swz,
                     &Ks[bb][(i * 32 + wv * 8) * 64]);
    };
    auto stageVT = [&](int t, int bb) {
        const int kv0 = kvb + t * 64;
#pragma unroll
        for (int i = 0; i < 2; ++i)
            gl2lds16(Vp + (size_t)(i * 32 + srow) * 2048 + kv0 + swz,
                     &VTs[bb][(i * 32 + wv * 8) * 64]);
    };

    stageK(0, 0); stageVT(0, 0);
    stageK(1, 1); stageVT(1, 1);

    f32x4 oacc[4][4];
#pragma unroll
    for (int qg = 0; qg < 4; ++qg)
#pragma unroll
        for (int t = 0; t < 4; ++t)
            oacc[qg][t] = (f32x4){0.f, 0.f, 0.f, 0.f};
    f32x4 lacc[4];
#pragma unroll
    for (int qg = 0; qg < 4; ++qg)
        lacc[qg] = (f32x4){0.f, 0.f, 0.f, 0.f};
    const bf16x8 ones8 = {(bf16)1.f, (bf16)1.f, (bf16)1.f, (bf16)1.f,
                          (bf16)1.f, (bf16)1.f, (bf16)1.f, (bf16)1.f};
    const f32x4  zero4 = (f32x4){0.f, 0.f, 0.f, 0.f};

    const int fcol0 = (quad ^ (f & 7)) * 8;
    const int fcol1 = ((4 + quad) ^ (f & 7)) * 8;

    // drain: 8 = steady (stage t+2, keep 2 tiles = 8 loads in flight),
    //        4 = t==14, 0 = t==15
    auto step = [&](int t, int bb, int drain) {
        if (drain == 8) { stageK(t + 2, (t + 2) & 3); stageVT(t + 2, (t + 2) & 3); }
        if (drain == 8)      asm volatile("s_waitcnt vmcnt(8)" ::: "memory");
        else if (drain == 4) asm volatile("s_waitcnt vmcnt(4)" ::: "memory");
        else                 asm volatile("s_waitcnt vmcnt(0)" ::: "memory");
        __builtin_amdgcn_s_barrier();

        // ---- S^T = K Q^T (K-frags read once, reused across 4 q-groups) ----
        bf16x8 kf0[4], kf1[4];
#pragma unroll
        for (int t4 = 0; t4 < 4; ++t4) {
            kf0[t4] = *(const bf16x8*)&Ks[bb][(t4 * 16 + f) * 64 + fcol0];
            kf1[t4] = *(const bf16x8*)&Ks[bb][(t4 * 16 + f) * 64 + fcol1];
        }
        bf16x8 pb8[4][2];
#pragma unroll
        for (int qg = 0; qg < 4; ++qg) {
            f32x4 s[4];
            __builtin_amdgcn_s_setprio(1);
#pragma unroll
            for (int t4 = 0; t4 < 4; ++t4) {
                s[t4] = MFMA16(kf0[t4], qf[qg][0], zero4);
                s[t4] = MFMA16(kf1[t4], qf[qg][1], s[t4]);
            }
            __builtin_amdgcn_s_setprio(0);
#pragma unroll
            for (int kt = 0; kt < 2; ++kt) {
#pragma unroll
                for (int r = 0; r < 4; ++r) {
                    pb8[qg][kt][r]     = (bf16)__builtin_amdgcn_exp2f(s[2 * kt][r]);
                    pb8[qg][kt][4 + r] = (bf16)__builtin_amdgcn_exp2f(s[2 * kt + 1][r]);
                }
                lacc[qg] = MFMA16(ones8, pb8[qg][kt], lacc[qg]);
            }
        }

        // ---- O^T += V^T P^T, full-rate 16x16x32 (V-frags reused 4x) ----
        __builtin_amdgcn_s_setprio(1);
#pragma unroll
        for (int dt = 0; dt < 4; ++dt) {
#pragma unroll
            for (int kt = 0; kt < 2; ++kt) {
                const int pc = ((kt * 4 + quad) ^ (f & 7)) * 8;
                bf16x8 vf = *(const bf16x8*)&VTs[bb][(dt * 16 + f) * 64 + pc];
#pragma unroll
                for (int qg = 0; qg < 4; ++qg)
                    oacc[qg][dt] = MFMA16(vf, pb8[qg][kt], oacc[qg][dt]);
            }
        }
        __builtin_amdgcn_s_setprio(0);
    };

    for (int tt = 0; tt < 12; tt += 4) {
        step(tt, 0, 8); step(tt + 1, 1, 8); step(tt + 2, 2, 8); step(tt + 3, 3, 8);
    }
    step(12, 0, 8); step(13, 1, 8); step(14, 2, 4); step(15, 3, 0);

    // ---- store unnormalized O-partial (bf16) + l-partial (fp32) ----
#pragma unroll
    for (int qg = 0; qg < 4; ++qg) {
        const int q = q0 + wv * 64 + qg * 16 + f;
        bf16* orow = Op + (size_t)q * 1024;
#pragma unroll
        for (int dt = 0; dt < 4; ++dt) {
            bf16x4 ov;
#pragma unroll
            for (int r = 0; r < 4; ++r)
                ov[r] = (bf16)oacc[qg][dt][r];
            *(bf16x4*)(orow + dt * 16 + quad * 4) = ov;
        }
        if (quad == 0)
            lp[q] = lacc[qg][0];
    }
}

extern "C" void kernel_launch(void* const* d_in, const int* in_sizes, int n_in,
                              void* d_out, int out_size, void* d_ws, size_t ws_size,
                              hipStream_t stream) {
    const float* x  = (const float*)d_in[0];
    const float* Wq = (const float*)d_in[1];
    const float* bq = (const float*)d_in[2];
    const float* Wk = (const float*)d_in[3];
    const float* bk = (const float*)d_in[4];
    const float* Wv = (const float*)d_in[5];
    const float* bv = (const float*)d_in[6];
    const float* Wo = (const float*)d_in[7];
    const float* bo = (const float*)d_in[8];
    float* out = (float*)d_out;

    bf16* xb    = (bf16*)d_ws;
    bf16* Wqb   = xb   + (size_t)MROWS * 1024;
    bf16* Wkb   = Wqb  + (size_t)1024 * 1024;
    bf16* Wvb   = Wkb  + (size_t)1024 * 1024;
    bf16* Wob   = Wvb  + (size_t)1024 * 1024;
    bf16* Q     = Wob  + (size_t)1024 * 1024;
    bf16* K     = Q    + (size_t)MROWS * 1024;
    bf16* VT    = K    + (size_t)MROWS * 1024;   // [B*1024 rows][2048 tokens, permuted]
    bf16* Opart = VT   + (size_t)MROWS * 1024;   // 2 halves, bf16, 16 MB
    float* lpart = (float*)(Opart + (size_t)2 * MROWS * 1024);  // 512 KB

    cast_all_kernel<<<4096, 256, 0, stream>>>(x, Wq, Wk, Wv, Wo, xb);

    qkv_kernel<<<dim3(32, 24), 256, 0, stream>>>(xb, Wqb, bq, Wkb, bk, Wvb, bv, Q, K, VT);
    attn_kernel<<<dim3(16, 32), 256, 0, stream>>>(Q, K, VT, Opart, lpart);
    oproj_kernel<<<dim3(32, 16), 256, 0, stream>>>(Opart, lpart, Wob, bo, out);
}

// Round 5
// 175.791 us; speedup vs baseline: 1.0748x; 1.0748x over previous
//
#include <hip/hip_runtime.h>
#include <stdint.h>

typedef __bf16 bf16;
typedef __bf16 bf16x4 __attribute__((ext_vector_type(4)));
typedef __bf16 bf16x8 __attribute__((ext_vector_type(8)));
typedef float f32x4 __attribute__((ext_vector_type(4)));

#define MFMA16(a, b, c) __builtin_amdgcn_mfma_f32_16x16x32_bf16((a), (b), (c), 0, 0, 0)

#define EMBED 1024
#define SEQ   2048
#define MROWS 4096
// 0.125 * log2(e): Q is pre-scaled so attn can use native v_exp_f32 (exp2).
#define ATTN_QSCALE 0.1803368801111f

__device__ __forceinline__ void gl2lds16(const bf16* g, bf16* l) {
    __builtin_amdgcn_global_load_lds(
        (const __attribute__((address_space(1))) void*)g,
        (__attribute__((address_space(3))) void*)l,
        16, 0, 0);
}

// ---------------------------------------------------------------------------
// fused fp32 -> bf16 cast of x + 4 weight matrices (contiguous dst region)
// ---------------------------------------------------------------------------
__global__ __launch_bounds__(256) void cast_all_kernel(
    const float* __restrict__ x,  const float* __restrict__ Wq,
    const float* __restrict__ Wk, const float* __restrict__ Wv,
    const float* __restrict__ Wo, bf16* __restrict__ dst) {
    const int blk = blockIdx.x;
    const float* src;
    size_t so, dofs;
    if (blk < 2048) {
        src = x; so = (size_t)blk * 2048; dofs = so;
    } else {
        const int w = (blk - 2048) >> 9;
        so  = (size_t)((blk - 2048) & 511) * 2048;
        src = (w == 0) ? Wq : (w == 1) ? Wk : (w == 2) ? Wv : Wo;
        dofs = (size_t)(4 + w) * 1024 * 1024 + so;
    }
    const size_t i = (size_t)threadIdx.x * 8;
    float4 a = *(const float4*)(src + so + i);
    float4 b = *(const float4*)(src + so + i + 4);
    bf16x8 o;
    o[0] = (bf16)a.x; o[1] = (bf16)a.y; o[2] = (bf16)a.z; o[3] = (bf16)a.w;
    o[4] = (bf16)b.x; o[5] = (bf16)b.y; o[6] = (bf16)b.z; o[7] = (bf16)b.w;
    *(bf16x8*)(dst + dofs + i) = o;
}

// ---------------------------------------------------------------------------
// Q/K GEMM path: 128x128 tile, BK=64, 4 waves 2x2, XOR-swizzled LDS.
// Double-buffered 1-deep pipeline: vmcnt(0) -> s_barrier -> stage(k+1) ->
// compute(k).
// ---------------------------------------------------------------------------
template <bool SCALE>
__device__ __forceinline__ void gemm_tile(const bf16* __restrict__ A,
                                          const bf16* __restrict__ W,
                                          const float* __restrict__ bias,
                                          bf16* __restrict__ C,
                                          int m0, int n0, bf16* smem) {
    const int lane = threadIdx.x & 63;
    const int wv   = threadIdx.x >> 6;
    const int wm   = (wv >> 1) * 64;
    const int wn   = (wv & 1) * 64;
    const int fr   = lane & 15;
    const int quad = lane >> 4;
    const int srow = wv * 8 + (lane >> 3);
    const int swz  = (((lane & 7) ^ ((lane >> 3) & 7))) * 8;

    f32x4 acc[4][4];
#pragma unroll
    for (int mt = 0; mt < 4; ++mt)
#pragma unroll
        for (int nt = 0; nt < 4; ++nt)
            acc[mt][nt] = (f32x4){0.f, 0.f, 0.f, 0.f};

    auto stage = [&](int kt, int bb) {
        bf16* As = smem + bb * 16384;
        bf16* Bs = As + 8192;
        const int k0 = kt * 64;
#pragma unroll
        for (int i = 0; i < 4; ++i) {
            gl2lds16(A + (size_t)(m0 + i * 32 + srow) * 1024 + k0 + swz,
                     &As[(i * 32 + wv * 8) * 64]);
            gl2lds16(W + (size_t)(n0 + i * 32 + srow) * 1024 + k0 + swz,
                     &Bs[(i * 32 + wv * 8) * 64]);
        }
    };

    stage(0, 0);
#pragma unroll
    for (int kt = 0; kt < 16; ++kt) {
        const int bb = kt & 1;
        asm volatile("s_waitcnt vmcnt(0)" ::: "memory");
        __builtin_amdgcn_s_barrier();
        if (kt < 15) stage(kt + 1, bb ^ 1);
        const bf16* As = smem + bb * 16384;
        const bf16* Bs = As + 8192;
#pragma unroll
        for (int ks = 0; ks < 2; ++ks) {
            const int fcol = ((ks * 4 + quad) ^ (fr & 7)) * 8;
            bf16x8 af[4], bfr[4];
#pragma unroll
            for (int t = 0; t < 4; ++t) {
                af[t]  = *(const bf16x8*)&As[(wm + t * 16 + fr) * 64 + fcol];
                bfr[t] = *(const bf16x8*)&Bs[(wn + t * 16 + fr) * 64 + fcol];
            }
            __builtin_amdgcn_s_setprio(1);
#pragma unroll
            for (int mt = 0; mt < 4; ++mt)
#pragma unroll
                for (int nt = 0; nt < 4; ++nt)
                    acc[mt][nt] = MFMA16(af[mt], bfr[nt], acc[mt][nt]);
            __builtin_amdgcn_s_setprio(0);
        }
    }

    float bv[4];
#pragma unroll
    for (int nt = 0; nt < 4; ++nt)
        bv[nt] = bias[n0 + wn + nt * 16 + fr];
    const int row4 = quad * 4;
#pragma unroll
    for (int mt = 0; mt < 4; ++mt)
#pragma unroll
        for (int nt = 0; nt < 4; ++nt)
#pragma unroll
            for (int r = 0; r < 4; ++r) {
                int m = m0 + wm + mt * 16 + row4 + r;
                int n = n0 + wn + nt * 16 + fr;
                float v = acc[mt][nt][r] + bv[nt];
                if (SCALE) v *= ATTN_QSCALE;
                C[(size_t)m * 1024 + n] = (bf16)v;
            }
}

// ---------------------------------------------------------------------------
// V^T GEMM path: swapped-operand MFMA + LDS round-trip transpose epilogue.
// Token axis of VT is PERMUTED within each 32-token chunk:
//   c' = quad*8 + t'*4 + r   <-  o = t'*16 + quad*4 + r
// ---------------------------------------------------------------------------
__device__ __forceinline__ void v_tile(const bf16* __restrict__ x,
                                       const bf16* __restrict__ Wv,
                                       const float* __restrict__ bias,
                                       bf16* __restrict__ VT,
                                       int m0, int n0, bf16* smem) {
    const int lane = threadIdx.x & 63;
    const int wv   = threadIdx.x >> 6;
    const int wmW  = (wv >> 1) * 64;
    const int wnT  = (wv & 1) * 64;
    const int f    = lane & 15;
    const int quad = lane >> 4;
    const int srow = wv * 8 + (lane >> 3);
    const int swz  = (((lane & 7) ^ ((lane >> 3) & 7))) * 8;

    f32x4 acc[4][4];
#pragma unroll
    for (int mt = 0; mt < 4; ++mt)
#pragma unroll
        for (int nt = 0; nt < 4; ++nt)
            acc[mt][nt] = (f32x4){0.f, 0.f, 0.f, 0.f};

    auto stage = [&](int kt, int bb) {
        bf16* As = smem + bb * 16384;
        bf16* Bs = As + 8192;
        const int k0 = kt * 64;
#pragma unroll
        for (int i = 0; i < 4; ++i) {
            gl2lds16(x  + (size_t)(m0 + i * 32 + srow) * 1024 + k0 + swz,
                     &As[(i * 32 + wv * 8) * 64]);
            gl2lds16(Wv + (size_t)(n0 + i * 32 + srow) * 1024 + k0 + swz,
                     &Bs[(i * 32 + wv * 8) * 64]);
        }
    };

    stage(0, 0);
#pragma unroll
    for (int kt = 0; kt < 16; ++kt) {
        const int bb = kt & 1;
        asm volatile("s_waitcnt vmcnt(0)" ::: "memory");
        __builtin_amdgcn_s_barrier();
        if (kt < 15) stage(kt + 1, bb ^ 1);
        const bf16* As = smem + bb * 16384;
        const bf16* Bs = As + 8192;
#pragma unroll
        for (int ks = 0; ks < 2; ++ks) {
            const int fcol = ((ks * 4 + quad) ^ (f & 7)) * 8;
            bf16x8 wf[4], xf[4];
#pragma unroll
            for (int t = 0; t < 4; ++t) {
                wf[t] = *(const bf16x8*)&Bs[(wmW + t * 16 + f) * 64 + fcol];
                xf[t] = *(const bf16x8*)&As[(wnT + t * 16 + f) * 64 + fcol];
            }
            __builtin_amdgcn_s_setprio(1);
#pragma unroll
            for (int mt = 0; mt < 4; ++mt)
#pragma unroll
                for (int nt = 0; nt < 4; ++nt)
                    acc[mt][nt] = MFMA16(wf[mt], xf[nt], acc[mt][nt]);
            __builtin_amdgcn_s_setprio(0);
        }
    }

    float4 b4[4];
#pragma unroll
    for (int mt = 0; mt < 4; ++mt)
        b4[mt] = *(const float4*)&bias[n0 + wmW + mt * 16 + quad * 4];

    __syncthreads();   // all waves done computing before smem reuse as scratch

#pragma unroll
    for (int mt = 0; mt < 4; ++mt)
#pragma unroll
        for (int nt = 0; nt < 4; ++nt) {
            const int tok = wnT + nt * 16 + f;
#pragma unroll
            for (int r = 0; r < 4; ++r) {
                const float bvr = (r == 0) ? b4[mt].x : (r == 1) ? b4[mt].y
                                : (r == 2) ? b4[mt].z : b4[mt].w;
                smem[(wmW + mt * 16 + quad * 4 + r) * 136 + tok] =
                    (bf16)(acc[mt][nt][r] + bvr);
            }
        }
    __syncthreads();

    const int n_r  = threadIdx.x >> 4;
    const int t8   = (threadIdx.x & 15) * 8;       // permuted positions [t8, t8+8)
    const int base = t8 & ~31;                     // 32-token chunk base
    const int u4   = ((t8 >> 3) & 3) * 4;          // quad-group within chunk
    const int bb   = m0 >> 11;
    const int tokg = (m0 & 2047) + t8;
#pragma unroll
    for (int p = 0; p < 8; ++p) {
        const int n_loc = p * 16 + n_r;
        const bf16* row = &smem[n_loc * 136];
        bf16x4 a = *(const bf16x4*)&row[base + u4];         // orig tokens t'=0
        bf16x4 b = *(const bf16x4*)&row[base + 16 + u4];    // orig tokens t'=1
        bf16x8 v = {a[0], a[1], a[2], a[3], b[0], b[1], b[2], b[3]};
        *(bf16x8*)&VT[((size_t)(bb * 1024 + n0 + n_loc)) * 2048 + tokg] = v;
    }
}

// merged Q/K/V projection (plain mapping -- R4's XCD chunking concentrated
// the slow V-tiles on 3 XCDs and regressed; reverted)
__global__ __launch_bounds__(256) void qkv_kernel(
    const bf16* __restrict__ x,
    const bf16* __restrict__ Wq, const float* __restrict__ bq,
    const bf16* __restrict__ Wk, const float* __restrict__ bk,
    const bf16* __restrict__ Wv, const float* __restrict__ bv,
    bf16* __restrict__ Q, bf16* __restrict__ K, bf16* __restrict__ VT) {
    __shared__ __align__(16) bf16 smem[32768];   // 2 bufs x (As 16KB + Bs 16KB)
    const int m0    = blockIdx.x * 128;
    const int which = blockIdx.y >> 3;
    const int n0    = (blockIdx.y & 7) * 128;
    if (which == 0)      gemm_tile<true>(x, Wq, bq, Q, m0, n0, smem);
    else if (which == 1) gemm_tile<false>(x, Wk, bk, K, m0, n0, smem);
    else                 v_tile(x, Wv, bv, VT, m0, n0, smem);
}

// ---------------------------------------------------------------------------
// O-proj GEMM, 128x64 tile, BK=64, 4 waves 2x2, fp32 out, same pipeline.
// ---------------------------------------------------------------------------
__global__ __launch_bounds__(256) void oproj_kernel(
    const bf16* __restrict__ A, const bf16* __restrict__ W,
    const float* __restrict__ bias, float* __restrict__ C) {
    const int m0 = blockIdx.x * 128;
    const int n0 = blockIdx.y * 64;

    __shared__ __align__(16) bf16 smem[24576];   // 2 bufs x (As 16KB + Bs 8KB)

    const int lane = threadIdx.x & 63;
    const int wv   = threadIdx.x >> 6;
    const int wm   = (wv >> 1) * 64;
    const int wn   = (wv & 1) * 32;
    const int fr   = lane & 15;
    const int quad = lane >> 4;
    const int srow = wv * 8 + (lane >> 3);
    const int swz  = (((lane & 7) ^ ((lane >> 3) & 7))) * 8;

    f32x4 acc[4][2];
#pragma unroll
    for (int mt = 0; mt < 4; ++mt)
#pragma unroll
        for (int nt = 0; nt < 2; ++nt)
            acc[mt][nt] = (f32x4){0.f, 0.f, 0.f, 0.f};

    auto stage = [&](int kt, int bb) {
        bf16* As = smem + bb * 12288;
        bf16* Bs = As + 8192;
        const int k0 = kt * 64;
#pragma unroll
        for (int i = 0; i < 4; ++i)
            gl2lds16(A + (size_t)(m0 + i * 32 + srow) * 1024 + k0 + swz,
                     &As[(i * 32 + wv * 8) * 64]);
#pragma unroll
        for (int i = 0; i < 2; ++i)
            gl2lds16(W + (size_t)(n0 + i * 32 + srow) * 1024 + k0 + swz,
                     &Bs[(i * 32 + wv * 8) * 64]);
    };

    stage(0, 0);
#pragma unroll
    for (int kt = 0; kt < 16; ++kt) {
        const int bb = kt & 1;
        asm volatile("s_waitcnt vmcnt(0)" ::: "memory");
        __builtin_amdgcn_s_barrier();
        if (kt < 15) stage(kt + 1, bb ^ 1);
        const bf16* As = smem + bb * 12288;
        const bf16* Bs = As + 8192;
#pragma unroll
        for (int ks = 0; ks < 2; ++ks) {
            const int fcol = ((ks * 4 + quad) ^ (fr & 7)) * 8;
            bf16x8 af[4], bfr[2];
#pragma unroll
            for (int t = 0; t < 4; ++t)
                af[t] = *(const bf16x8*)&As[(wm + t * 16 + fr) * 64 + fcol];
#pragma unroll
            for (int t = 0; t < 2; ++t)
                bfr[t] = *(const bf16x8*)&Bs[(wn + t * 16 + fr) * 64 + fcol];
            __builtin_amdgcn_s_setprio(1);
#pragma unroll
            for (int mt = 0; mt < 4; ++mt)
#pragma unroll
                for (int nt = 0; nt < 2; ++nt)
                    acc[mt][nt] = MFMA16(af[mt], bfr[nt], acc[mt][nt]);
            __builtin_amdgcn_s_setprio(0);
        }
    }

    float bv[2];
#pragma unroll
    for (int nt = 0; nt < 2; ++nt)
        bv[nt] = bias[n0 + wn + nt * 16 + fr];
    const int row4 = quad * 4;
#pragma unroll
    for (int mt = 0; mt < 4; ++mt)
#pragma unroll
        for (int nt = 0; nt < 2; ++nt)
#pragma unroll
            for (int r = 0; r < 4; ++r) {
                int m = m0 + wm + mt * 16 + row4 + r;
                int n = n0 + wn + nt * 16 + fr;
                C[(size_t)m * 1024 + n] = acc[mt][nt][r] + bv[nt];
            }
}

// ---------------------------------------------------------------------------
// Flash attention v13: ring-4 buffers as v11/v12, but CROSS-TILE pipelined:
// step t computes QK^T(t+1) interleaved with PV(t) per q-group
// (QK(u) -> PV(u) -> exp(u)), so PV MFMAs feed the matrix pipe while the
// exp VALU of the next tile runs, breaking the per-wave serial QK->exp->PV
// chain.  Steady-state wait is vmcnt(4) (tile t+1 resident; stage depth t+2
// is the ring-4 max).  Double P-buffer pbA/pbB.  XCD-chunked block swizzle.
// ---------------------------------------------------------------------------
__global__ __launch_bounds__(256, 2) void attn_kernel(
    const bf16* __restrict__ Q, const bf16* __restrict__ K,
    const bf16* __restrict__ VT, bf16* __restrict__ Opart,
    float* __restrict__ lpart) {
    const int tid  = threadIdx.x;
    const int lane = tid & 63;
    const int wv   = tid >> 6;       // 0..3
    const int quad = lane >> 4;
    const int f    = lane & 15;
    const int lin  = blockIdx.y * 16 + blockIdx.x;   // 0..511
    const int sw   = (lin & 7) * 64 + (lin >> 3);    // XCD chunks of 64
    const int qh   = sw & 15;
    const int bh   = sw >> 4;        // 0..31
    const int qt   = qh >> 1;
    const int half = qh & 1;
    const int q0   = qt * 256;
    const int kvb  = half * 1024;
    const int b    = bh >> 4;
    const int h    = bh & 15;

    const bf16* Qp = Q + ((size_t)b * SEQ) * 1024 + (size_t)h * 64;
    const bf16* Kp = K + ((size_t)b * SEQ) * 1024 + (size_t)h * 64;
    const bf16* Vp = VT + ((size_t)(b * 1024 + h * 64)) * 2048;   // [d][tok']
    bf16*  Op = Opart + (size_t)half * MROWS * 1024
                      + ((size_t)b * SEQ) * 1024 + (size_t)h * 64;
    float* lp = lpart + ((size_t)(half * 2 + b) * 16 + h) * SEQ;

    __shared__ bf16 Ks[4][64 * 64];    // ring-4 [kv][d], swizzled 16B groups
    __shared__ bf16 VTs[4][64 * 64];   // ring-4 [d][kv'], swizzled 16B groups

    // Q fragments: wave handles 64 q-rows (4 groups of 16); pre-scaled.
    bf16x8 qf[4][2];
#pragma unroll
    for (int qg = 0; qg < 4; ++qg) {
        const bf16* qrow = Qp + (size_t)(q0 + wv * 64 + qg * 16 + f) * 1024;
        qf[qg][0] = *(const bf16x8*)(qrow + quad * 8);
        qf[qg][1] = *(const bf16x8*)(qrow + 32 + quad * 8);
    }

    const int srow = wv * 8 + (lane >> 3);
    const int swz  = (((lane & 7) ^ ((lane >> 3) & 7))) * 8;
    auto stageK = [&](int t, int bb) {
        const int kv0 = kvb + t * 64;
#pragma unroll
        for (int i = 0; i < 2; ++i)
            gl2lds16(Kp + (size_t)(kv0 + i * 32 + srow) * 1024 + swz,
                     &Ks[bb][(i * 32 + wv * 8) * 64]);
    };
    auto stageVT = [&](int t, int bb) {
        const int kv0 = kvb + t * 64;
#pragma unroll
        for (int i = 0; i < 2; ++i)
            gl2lds16(Vp + (size_t)(i * 32 + srow) * 2048 + kv0 + swz,
                     &VTs[bb][(i * 32 + wv * 8) * 64]);
    };

    stageK(0, 0); stageVT(0, 0);
    stageK(1, 1); stageVT(1, 1);

    f32x4 oacc[4][4];
#pragma unroll
    for (int qg = 0; qg < 4; ++qg)
#pragma unroll
        for (int t = 0; t < 4; ++t)
            oacc[qg][t] = (f32x4){0.f, 0.f, 0.f, 0.f};
    f32x4 lacc[4];
#pragma unroll
    for (int qg = 0; qg < 4; ++qg)
        lacc[qg] = (f32x4){0.f, 0.f, 0.f, 0.f};
    const bf16x8 ones8 = {(bf16)1.f, (bf16)1.f, (bf16)1.f, (bf16)1.f,
                          (bf16)1.f, (bf16)1.f, (bf16)1.f, (bf16)1.f};
    const f32x4  zero4 = (f32x4){0.f, 0.f, 0.f, 0.f};

    const int fcol0 = (quad ^ (f & 7)) * 8;
    const int fcol1 = ((4 + quad) ^ (f & 7)) * 8;

    bf16x8 pbA[4][2], pbB[4][2];

    // ---- prologue: wait tile 0, compute QK(0) -> pbA ----
    asm volatile("s_waitcnt vmcnt(4)" ::: "memory");
    __builtin_amdgcn_s_barrier();
    {
        bf16x8 kf0[4], kf1[4];
#pragma unroll
        for (int t4 = 0; t4 < 4; ++t4) {
            kf0[t4] = *(const bf16x8*)&Ks[0][(t4 * 16 + f) * 64 + fcol0];
            kf1[t4] = *(const bf16x8*)&Ks[0][(t4 * 16 + f) * 64 + fcol1];
        }
#pragma unroll
        for (int qg = 0; qg < 4; ++qg) {
            f32x4 s[4];
            __builtin_amdgcn_s_setprio(1);
#pragma unroll
            for (int t4 = 0; t4 < 4; ++t4) {
                s[t4] = MFMA16(kf0[t4], qf[qg][0], zero4);
                s[t4] = MFMA16(kf1[t4], qf[qg][1], s[t4]);
            }
            __builtin_amdgcn_s_setprio(0);
#pragma unroll
            for (int kt = 0; kt < 2; ++kt) {
#pragma unroll
                for (int r = 0; r < 4; ++r) {
                    pbA[qg][kt][r]     = (bf16)__builtin_amdgcn_exp2f(s[2 * kt][r]);
                    pbA[qg][kt][4 + r] = (bf16)__builtin_amdgcn_exp2f(s[2 * kt + 1][r]);
                }
                lacc[qg] = MFMA16(ones8, pbA[qg][kt], lacc[qg]);
            }
        }
    }

    // step t: stage(t+2) | wait tile t+1 | barrier | QK(t+1)∥PV(t) per group
    auto step = [&](int t, bf16x8 (&pbc)[4][2], bf16x8 (&pbn)[4][2],
                    int drain, bool doStage, bool doQK) {
        if (doStage) { stageK(t + 2, (t + 2) & 3); stageVT(t + 2, (t + 2) & 3); }
        if (drain == 4) asm volatile("s_waitcnt vmcnt(4)" ::: "memory");
        else            asm volatile("s_waitcnt vmcnt(0)" ::: "memory");
        __builtin_amdgcn_s_barrier();
        const int bq = (t + 1) & 3;
        const int bp = t & 3;

        bf16x8 kf0[4], kf1[4];
        if (doQK) {
#pragma unroll
            for (int t4 = 0; t4 < 4; ++t4) {
                kf0[t4] = *(const bf16x8*)&Ks[bq][(t4 * 16 + f) * 64 + fcol0];
                kf1[t4] = *(const bf16x8*)&Ks[bq][(t4 * 16 + f) * 64 + fcol1];
            }
        }
#pragma unroll
        for (int u = 0; u < 4; ++u) {
            f32x4 s[4];
            if (doQK) {
                __builtin_amdgcn_s_setprio(1);
#pragma unroll
                for (int t4 = 0; t4 < 4; ++t4) {
                    s[t4] = MFMA16(kf0[t4], qf[u][0], zero4);
                    s[t4] = MFMA16(kf1[t4], qf[u][1], s[t4]);
                }
                __builtin_amdgcn_s_setprio(0);
            }
            // PV for dt = u on tile t (P from previous tile's QK)
            __builtin_amdgcn_s_setprio(1);
#pragma unroll
            for (int kt = 0; kt < 2; ++kt) {
                const int pc = ((kt * 4 + quad) ^ (f & 7)) * 8;
                bf16x8 vf = *(const bf16x8*)&VTs[bp][(u * 16 + f) * 64 + pc];
#pragma unroll
                for (int qg = 0; qg < 4; ++qg)
                    oacc[qg][u] = MFMA16(vf, pbc[qg][kt], oacc[qg][u]);
            }
            __builtin_amdgcn_s_setprio(0);
            if (doQK) {
#pragma unroll
                for (int kt = 0; kt < 2; ++kt) {
#pragma unroll
                    for (int r = 0; r < 4; ++r) {
                        pbn[u][kt][r]     = (bf16)__builtin_amdgcn_exp2f(s[2 * kt][r]);
                        pbn[u][kt][4 + r] = (bf16)__builtin_amdgcn_exp2f(s[2 * kt + 1][r]);
                    }
                    lacc[u] = MFMA16(ones8, pbn[u][kt], lacc[u]);
                }
            }
        }
    };

    for (int tt = 0; tt < 14; tt += 2) {
        step(tt,     pbA, pbB, 4, true, true);
        step(tt + 1, pbB, pbA, 4, true, true);
    }
    step(14, pbA, pbB, 0, false, true);   // waits tile 15; QK(15) -> pbB
    step(15, pbB, pbA, 0, false, false);  // PV(15) only

    // ---- store unnormalized O-partial (bf16) + l-partial (fp32) ----
#pragma unroll
    for (int qg = 0; qg < 4; ++qg) {
        const int q = q0 + wv * 64 + qg * 16 + f;
        bf16* orow = Op + (size_t)q * 1024;
#pragma unroll
        for (int dt = 0; dt < 4; ++dt) {
            bf16x4 ov;
#pragma unroll
            for (int r = 0; r < 4; ++r)
                ov[r] = (bf16)oacc[qg][dt][r];
            *(bf16x4*)(orow + dt * 16 + quad * 4) = ov;
        }
        if (quad == 0)
            lp[q] = lacc[qg][0];
    }
}

// ---------------------------------------------------------------------------
// combine: O = (Op1 + Op2) / (l1 + l2), bf16 out.
// ---------------------------------------------------------------------------
__global__ __launch_bounds__(256) void combine_kernel(
    const bf16* __restrict__ Opart, const float* __restrict__ lpart,
    bf16* __restrict__ O) {
    const int gid = blockIdx.x * 256 + threadIdx.x;     // 0..524287
    const int row = gid >> 7;                           // 0..4095
    const int c8  = (gid & 127) * 8;
    const int b   = row >> 11;
    const int tok = row & 2047;
    const int h   = c8 >> 6;

    const float l = lpart[((size_t)(0 * 2 + b) * 16 + h) * SEQ + tok]
                  + lpart[((size_t)(1 * 2 + b) * 16 + h) * SEQ + tok];
    const float inv = 1.0f / l;

    const size_t off = (size_t)row * 1024 + c8;
    bf16x8 a = *(const bf16x8*)&Opart[off];
    bf16x8 c = *(const bf16x8*)&Opart[(size_t)MROWS * 1024 + off];
    bf16x8 o;
#pragma unroll
    for (int i = 0; i < 8; ++i)
        o[i] = (bf16)(((float)a[i] + (float)c[i]) * inv);
    *(bf16x8*)&O[off] = o;
}

extern "C" void kernel_launch(void* const* d_in, const int* in_sizes, int n_in,
                              void* d_out, int out_size, void* d_ws, size_t ws_size,
                              hipStream_t stream) {
    const float* x  = (const float*)d_in[0];
    const float* Wq = (const float*)d_in[1];
    const float* bq = (const float*)d_in[2];
    const float* Wk = (const float*)d_in[3];
    const float* bk = (const float*)d_in[4];
    const float* Wv = (const float*)d_in[5];
    const float* bv = (const float*)d_in[6];
    const float* Wo = (const float*)d_in[7];
    const float* bo = (const float*)d_in[8];
    float* out = (float*)d_out;

    bf16* xb    = (bf16*)d_ws;
    bf16* Wqb   = xb   + (size_t)MROWS * 1024;
    bf16* Wkb   = Wqb  + (size_t)1024 * 1024;
    bf16* Wvb   = Wkb  + (size_t)1024 * 1024;
    bf16* Wob   = Wvb  + (size_t)1024 * 1024;
    bf16* Q     = Wob  + (size_t)1024 * 1024;
    bf16* K     = Q    + (size_t)MROWS * 1024;
    bf16* VT    = K    + (size_t)MROWS * 1024;   // [B*1024 rows][2048 tokens, permuted]
    bf16* O     = VT   + (size_t)MROWS * 1024;
    bf16* Opart = O    + (size_t)MROWS * 1024;   // 2 halves, bf16, 16 MB
    float* lpart = (float*)(Opart + (size_t)2 * MROWS * 1024);  // 512 KB

    cast_all_kernel<<<4096, 256, 0, stream>>>(x, Wq, Wk, Wv, Wo, xb);

    qkv_kernel<<<dim3(32, 24), 256, 0, stream>>>(xb, Wqb, bq, Wkb, bk, Wvb, bv, Q, K, VT);
    attn_kernel<<<dim3(16, 32), 256, 0, stream>>>(Q, K, VT, Opart, lpart);
    combine_kernel<<<2048, 256, 0, stream>>>(Opart, lpart, O);
    oproj_kernel<<<dim3(32, 16), 256, 0, stream>>>(O, Wob, bo, out);
}